// Round 2
// baseline (483.766 us; speedup 1.0000x reference)
//
#include <hip/hip_runtime.h>

#define DIM 256
#define NNB 24
#define NEL 8192
#define ROWS 16
#define NT 512
#define CUTOFF 5.0f

__device__ __forceinline__ float fast_silu(float x){
  float e = __builtin_amdgcn_exp2f(-1.44269504088896340f * x);
  return x * __builtin_amdgcn_rcpf(1.0f + e);
}

// MODE 0: dst = silu(A@W + bias)                      -> dstLds
// MODE 1: dst = silu(A@W + bias + extraLds)           -> dstLds
// MODE 2: dst = silu(A@W + bias + extraGbl)           -> dstLds
// MODE 3: out = (silu(A@W + bias) + extraLds) * scl   -> outGbl
template<int MODE>
__device__ __forceinline__ void gemm256(
    const float* Asrc, const float* __restrict__ W, const float* __restrict__ bias,
    const float* extraLds, const float* __restrict__ extraGbl,
    float* dstLds, float* __restrict__ outGbl, float scl, int n0, int t)
{
  const int g  = t >> 6;            // 0..7 -> rows 2g, 2g+1
  const int c0 = (t & 63) << 2;     // 4 consecutive cols
  float acc0[4] = {0.f,0.f,0.f,0.f};
  float acc1[4] = {0.f,0.f,0.f,0.f};
  const float* a0p = Asrc + (2*g)*DIM;
  const float* a1p = a0p + DIM;
  for (int i0 = 0; i0 < DIM; i0 += 4){
    float4 a0 = *(const float4*)(a0p + i0);
    float4 a1 = *(const float4*)(a1p + i0);
    float a0a[4] = {a0.x, a0.y, a0.z, a0.w};
    float a1a[4] = {a1.x, a1.y, a1.z, a1.w};
    #pragma unroll
    for (int ii = 0; ii < 4; ii++){
      float4 wv = *(const float4*)(W + (i0+ii)*DIM + c0);
      acc0[0] += a0a[ii]*wv.x; acc0[1] += a0a[ii]*wv.y;
      acc0[2] += a0a[ii]*wv.z; acc0[3] += a0a[ii]*wv.w;
      acc1[0] += a1a[ii]*wv.x; acc1[1] += a1a[ii]*wv.y;
      acc1[2] += a1a[ii]*wv.z; acc1[3] += a1a[ii]*wv.w;
    }
  }
  float4 bv = *(const float4*)(bias + c0);
  float bb[4] = {bv.x, bv.y, bv.z, bv.w};
  #pragma unroll
  for (int m = 0; m < 4; m++){ acc0[m] += bb[m]; acc1[m] += bb[m]; }

  if (MODE == 1){
    float4 e0 = *(const float4*)(extraLds + (2*g)*DIM + c0);
    float4 e1 = *(const float4*)(extraLds + (2*g+1)*DIM + c0);
    acc0[0]+=e0.x; acc0[1]+=e0.y; acc0[2]+=e0.z; acc0[3]+=e0.w;
    acc1[0]+=e1.x; acc1[1]+=e1.y; acc1[2]+=e1.z; acc1[3]+=e1.w;
  }
  if (MODE == 2){
    float4 m0 = *(const float4*)(extraGbl + (n0+2*g)*DIM + c0);
    float4 m1 = *(const float4*)(extraGbl + (n0+2*g+1)*DIM + c0);
    acc0[0]+=m0.x; acc0[1]+=m0.y; acc0[2]+=m0.z; acc0[3]+=m0.w;
    acc1[0]+=m1.x; acc1[1]+=m1.y; acc1[2]+=m1.z; acc1[3]+=m1.w;
  }
  #pragma unroll
  for (int m = 0; m < 4; m++){ acc0[m] = fast_silu(acc0[m]); acc1[m] = fast_silu(acc1[m]); }

  if (MODE == 3){
    float4 e0 = *(const float4*)(extraLds + (2*g)*DIM + c0);
    float4 e1 = *(const float4*)(extraLds + (2*g+1)*DIM + c0);
    float4 o0 = make_float4((acc0[0]+e0.x)*scl, (acc0[1]+e0.y)*scl,
                            (acc0[2]+e0.z)*scl, (acc0[3]+e0.w)*scl);
    float4 o1 = make_float4((acc1[0]+e1.x)*scl, (acc1[1]+e1.y)*scl,
                            (acc1[2]+e1.z)*scl, (acc1[3]+e1.w)*scl);
    *(float4*)(outGbl + (n0+2*g)*DIM + c0)   = o0;
    *(float4*)(outGbl + (n0+2*g+1)*DIM + c0) = o1;
  } else {
    *(float4*)(dstLds + (2*g)*DIM + c0)   = make_float4(acc0[0],acc0[1],acc0[2],acc0[3]);
    *(float4*)(dstLds + (2*g+1)*DIM + c0) = make_float4(acc1[0],acc1[1],acc1[2],acc1[3]);
  }
}

__global__ __launch_bounds__(NT, 4)
void fused_moon_kernel(
    const float* __restrict__ elec, const float* __restrict__ msg,
    const float* __restrict__ rpos, const float* __restrict__ rnb,
    const int* __restrict__ s,    const int* __restrict__ snb,
    const float* __restrict__ hinit,
    const float* __restrict__ Win,  const float* __restrict__ bin,
    const float* __restrict__ eesc, const float* __restrict__ eek,
    const float* __restrict__ eeb,  const float* __restrict__ Wf,
    const float* __restrict__ bfb,  const float* __restrict__ Wsame,
    const float* __restrict__ Wdiff,
    const float* __restrict__ W1, const float* __restrict__ b1,
    const float* __restrict__ W2, const float* __restrict__ b2,
    const float* __restrict__ W3, const float* __restrict__ b3,
    const float* __restrict__ scalep, float* __restrict__ out)
{
  // sAB: phase0-1 = elec rows (4096 floats); phase2 = beta[16][24][16] (6144); phase3 = t1 (4096)
  __shared__ float sAB[ROWS*NNB*16];
  __shared__ float sE1[ROWS*DIM];
  __shared__ float sH [ROWS*DIM];
  __shared__ float sK[128], sKb[32], sWfw[640], sbf[16], sSc[8];
  __shared__ int   sMask[ROWS*NNB];

  const int t  = threadIdx.x;
  const int n0 = blockIdx.x * ROWS;

  // ---- Phase 0: stage elec rows (float4 x2 per thread) + tiny weights ----
  {
    const float4* ep = (const float4*)(elec + n0*DIM);   // 1024 float4s
    float4 v0 = ep[t];
    float4 v1 = ep[t + NT];
    *(float4*)&sAB[t*4]        = v0;
    *(float4*)&sAB[(t+NT)*4]   = v1;
  }
  for (int p=t; p<640; p+=NT) sWfw[p]=Wf[p];
  for (int p=t; p<128; p+=NT) sK[p]=eek[p];
  for (int p=t; p<32;  p+=NT) sKb[p]=eeb[p];
  for (int p=t; p<16;  p+=NT) sbf[p]=bfb[p];
  for (int p=t; p<8;   p+=NT) sSc[p]=eesc[p];
  __syncthreads();

  // ---- Phase 1: elec1 = silu(elec @ W_in + b_in) -> sE1 ----
  gemm256<0>(sAB, Win, bin, nullptr, nullptr, sE1, nullptr, 0.f, n0, t);
  __syncthreads();

  // ---- Phase 2a: pairwise filter -> beta into sAB, spin mask ----
  if (t < ROWS*NNB) {
    const int rr = t / NNB;
    const int k  = t - rr*NNB;
    const int n  = n0 + rr;
    const float* rp  = rpos + n*3;
    const float* rnp = rnb + (n*NNB + k)*3;
    float dx = rnp[0] - rp[0];
    float dy = rnp[1] - rp[1];
    float dz = rnp[2] - rp[2];
    float dist = sqrtf(dx*dx + dy*dy + dz*dz + 1e-12f);
    float feats[4] = {dist, dx, dy, dz};
    float h[32];
    #pragma unroll
    for (int f4 = 0; f4 < 8; f4++){
      float4 a4 = *(const float4*)&sKb[4*f4];
      float av[4] = {a4.x, a4.y, a4.z, a4.w};
      #pragma unroll
      for (int i = 0; i < 4; i++){
        float4 kv = *(const float4*)&sK[i*32 + 4*f4];
        av[0]+=feats[i]*kv.x; av[1]+=feats[i]*kv.y; av[2]+=feats[i]*kv.z; av[3]+=feats[i]*kv.w;
      }
      h[4*f4+0]=fast_silu(av[0]); h[4*f4+1]=fast_silu(av[1]);
      h[4*f4+2]=fast_silu(av[2]); h[4*f4+3]=fast_silu(av[3]);
    }
    float env[8];
    #pragma unroll
    for (int e = 0; e < 8; e++){
      float q = dist * __builtin_amdgcn_rcpf(sSc[e]);
      env[e] = __builtin_amdgcn_exp2f(-1.44269504088896340f * q * q);
    }
    float xx = dist * (1.0f/CUTOFF);
    float cut = (dist < CUTOFF) ? (1.0f-xx)*(1.0f-xx)*(1.0f+2.0f*xx) : 0.0f;
    float* bout = &sAB[(rr*NNB + k)*16];
    #pragma unroll
    for (int j4 = 0; j4 < 4; j4++){
      float4 a4 = *(const float4*)&sbf[4*j4];
      float av[4] = {a4.x, a4.y, a4.z, a4.w};
      #pragma unroll
      for (int f = 0; f < 40; f++){
        float val = (f < 32) ? h[f] : env[f-32];
        float4 wv = *(const float4*)&sWfw[f*16 + 4*j4];
        av[0]+=val*wv.x; av[1]+=val*wv.y; av[2]+=val*wv.z; av[3]+=val*wv.w;
      }
      *(float4*)(bout + 4*j4) = make_float4(av[0]*cut, av[1]*cut, av[2]*cut, av[3]*cut);
    }
    sMask[rr*NNB + k] = (s[n] == snb[n*NNB + k]) ? 1 : 0;
  }
  __syncthreads();

  // ---- Phase 2b: hinit_msg -> sH.  128 threads/row-group, 2 dims/thread ----
  {
    const int rg = t >> 7;           // 0..3
    const int d0 = (t & 127) << 1;
    float2 wsv[16], wdv[16];
    #pragma unroll
    for (int j = 0; j < 16; j++){
      wsv[j] = *(const float2*)(Wsame + j*DIM + d0);
      wdv[j] = *(const float2*)(Wdiff + j*DIM + d0);
    }
    for (int rr = 0; rr < 4; rr++){
      const int r = rg*4 + rr;
      const int n = n0 + r;
      float2 e1v = *(const float2*)&sE1[r*DIM + d0];
      float ax = 0.f, ay = 0.f;
      for (int k = 0; k < NNB; k++){
        const float* bp = &sAB[(r*NNB + k)*16];
        float bb[16];
        *(float4*)&bb[0]  = *(const float4*)(bp);
        *(float4*)&bb[4]  = *(const float4*)(bp+4);
        *(float4*)&bb[8]  = *(const float4*)(bp+8);
        *(float4*)&bb[12] = *(const float4*)(bp+12);
        float2 hv = *(const float2*)(hinit + ((size_t)(n*NNB + k) << 8) + d0);
        float sx = fast_silu(e1v.x + hv.x);
        float sy = fast_silu(e1v.y + hv.y);
        float gx = 0.f, gy = 0.f;
        if (sMask[r*NNB + k]){
          #pragma unroll
          for (int j = 0; j < 16; j++){ gx += bb[j]*wsv[j].x; gy += bb[j]*wsv[j].y; }
        } else {
          #pragma unroll
          for (int j = 0; j < 16; j++){ gx += bb[j]*wdv[j].x; gy += bb[j]*wdv[j].y; }
        }
        ax += sx*gx; ay += sy*gy;
      }
      *(float2*)&sH[r*DIM + d0] = make_float2(ax, ay);
    }
  }
  __syncthreads();

  const float scl = scalep[0];

  // ---- Phase 3: three chained GEMMs ----
  gemm256<1>(sE1, W1, b1, sH, nullptr, sAB, nullptr, 0.f, n0, t);   // t1 -> sAB
  __syncthreads();
  gemm256<2>(sAB, W2, b2, nullptr, msg, sH, nullptr, 0.f, n0, t);   // t2 -> sH
  __syncthreads();
  gemm256<3>(sH, W3, b3, sE1, nullptr, nullptr, out, scl, n0, t);   // final -> out
}

extern "C" void kernel_launch(void* const* d_in, const int* in_sizes, int n_in,
                              void* d_out, int out_size, void* d_ws, size_t ws_size,
                              hipStream_t stream) {
  (void)in_sizes; (void)n_in; (void)d_ws; (void)ws_size; (void)out_size;
  const float* elec  = (const float*)d_in[0];
  const float* msg   = (const float*)d_in[1];
  const float* rpos  = (const float*)d_in[2];
  const float* rnb   = (const float*)d_in[3];
  const int*   s     = (const int*)d_in[4];
  const int*   snb   = (const int*)d_in[5];
  const float* hinit = (const float*)d_in[6];
  const float* Win   = (const float*)d_in[7];
  const float* bin   = (const float*)d_in[8];
  const float* eesc  = (const float*)d_in[9];
  const float* eek   = (const float*)d_in[10];
  const float* eeb   = (const float*)d_in[11];
  const float* Wf    = (const float*)d_in[12];
  const float* bfb   = (const float*)d_in[13];
  const float* Wsame = (const float*)d_in[14];
  const float* Wdiff = (const float*)d_in[15];
  const float* W1    = (const float*)d_in[16];
  const float* b1    = (const float*)d_in[17];
  const float* W2    = (const float*)d_in[18];
  const float* b2    = (const float*)d_in[19];
  const float* W3    = (const float*)d_in[20];
  const float* b3    = (const float*)d_in[21];
  const float* scl   = (const float*)d_in[22];
  float* outp        = (float*)d_out;

  fused_moon_kernel<<<dim3(NEL/ROWS), dim3(NT), 0, stream>>>(
      elec, msg, rpos, rnb, s, snb, hinit,
      Win, bin, eesc, eek, eeb, Wf, bfb, Wsame, Wdiff,
      W1, b1, W2, b2, W3, b3, scl, outp);
}

// Round 3
// 392.038 us; speedup vs baseline: 1.2340x; 1.2340x over previous
//
#include <hip/hip_runtime.h>

#define DIM 256
#define PDIM 260          // padded LDS row stride (floats): breaks 16-way bank aliasing
#define NNB 24
#define NEL 8192
#define ROWS 16
#define NT 512
#define CUTOFF 5.0f

typedef unsigned int u32;
typedef unsigned short u16;
typedef __attribute__((ext_vector_type(8))) short bf16x8;
typedef __attribute__((ext_vector_type(4))) float f32x4;

__device__ __forceinline__ u16 f2b(float f){
  union{float f;u32 i;}v; v.f=f;
  u32 r = v.i + 0x7fffu + ((v.i>>16)&1u);   // RNE
  return (u16)(r>>16);
}
__device__ __forceinline__ float fast_silu(float x){
  float e = __builtin_amdgcn_exp2f(-1.44269504088896340f * x);
  return x * __builtin_amdgcn_rcpf(1.0f + e);
}

// Pre-pass: Wt[mat][n][k] = bf16(W[k][n]); 4 mats of 256x256 -> d_ws (512 KB)
__global__ __launch_bounds__(256)
void wprep(const float* __restrict__ W0, const float* __restrict__ W1,
           const float* __restrict__ W2, const float* __restrict__ W3,
           u16* __restrict__ ws){
  const int mat = blockIdx.x >> 8;
  const int n   = blockIdx.x & 255;
  const int k   = threadIdx.x;
  const float* W = (mat==0)?W0:(mat==1)?W1:(mat==2)?W2:W3;
  ws[(mat<<16) + (n<<8) + k] = f2b(W[(k<<8) + n]);
}

// MFMA GEMM: C[16][256] = silu(A[16][256] @ W[256][256] + bias [+extra]) variants.
// Wt is bf16 W^T [n][k]. A is LDS f32 stride PDIM.
// MODE 0: -> sE1                    (elec1)
// MODE 1: + sR1 (hmsg), -> sR1      (t1; in-place per-element-owner, no inner barrier)
// MODE 2: + msg(global), inner barrier, -> sR1   (t2 overwrites t1)
// MODE 3: out = (silu(.) + sE1) * scl -> global
template<int MODE>
__device__ __forceinline__ void gemm_mfma(
    const float* A, float* sE1, float* sR1,
    const u16* __restrict__ Wt, const float* __restrict__ bias,
    const float* __restrict__ extraGbl, float* __restrict__ outGbl,
    float scl, int n0, int t)
{
  const int lane = t & 63;
  const int ln   = lane & 15;     // A-row m / B-row n within tile
  const int quad = lane >> 4;     // 0..3
  const int nt0  = (t >> 6) << 1; // wave -> 2 N-tiles
  f32x4 acc0 = {0.f,0.f,0.f,0.f};
  f32x4 acc1 = {0.f,0.f,0.f,0.f};
  const float* arow = A + ln*PDIM;
  const u16* bp0 = Wt + (nt0*16 + ln)*DIM;
  const u16* bp1 = bp0 + 16*DIM;
  #pragma unroll
  for (int ks = 0; ks < 8; ks++){
    const int k0 = ks*32 + quad*8;
    float4 a01 = *(const float4*)(arow + k0);
    float4 a23 = *(const float4*)(arow + k0 + 4);
    bf16x8 af;
    af[0]=(short)f2b(a01.x); af[1]=(short)f2b(a01.y);
    af[2]=(short)f2b(a01.z); af[3]=(short)f2b(a01.w);
    af[4]=(short)f2b(a23.x); af[5]=(short)f2b(a23.y);
    af[6]=(short)f2b(a23.z); af[7]=(short)f2b(a23.w);
    bf16x8 b0 = *(const bf16x8*)(bp0 + k0);
    bf16x8 b1 = *(const bf16x8*)(bp1 + k0);
    acc0 = __builtin_amdgcn_mfma_f32_16x16x32_bf16(af, b0, acc0, 0, 0, 0);
    acc1 = __builtin_amdgcn_mfma_f32_16x16x32_bf16(af, b1, acc1, 0, 0, 0);
  }
  if (MODE == 2) __syncthreads();   // all k-loop reads of t1 done before t2 writes
  #pragma unroll
  for (int r = 0; r < 4; r++){
    const int m = quad*4 + r;       // C/D row = (lane>>4)*4 + reg
    #pragma unroll
    for (int tt = 0; tt < 2; tt++){
      const int n = (nt0+tt)*16 + ln;   // C/D col = lane&15
      float v = (tt ? acc1[r] : acc0[r]) + bias[n];
      if (MODE == 1) v += sR1[m*PDIM + n];
      if (MODE == 2) v += extraGbl[(size_t)(n0+m)*DIM + n];
      v = fast_silu(v);
      if (MODE == 0)      sE1[m*PDIM + n] = v;
      else if (MODE == 3) outGbl[(size_t)(n0+m)*DIM + n] = (v + sE1[m*PDIM + n]) * scl;
      else                sR1[m*PDIM + n] = v;
    }
  }
}

__global__ __launch_bounds__(NT, 4)
void fused_moon_kernel(
    const float* __restrict__ elec, const float* __restrict__ msg,
    const float* __restrict__ rpos, const float* __restrict__ rnb,
    const int* __restrict__ s,    const int* __restrict__ snb,
    const float* __restrict__ hinit,
    const float* __restrict__ bin,
    const float* __restrict__ eesc, const float* __restrict__ eek,
    const float* __restrict__ eeb,  const float* __restrict__ Wf,
    const float* __restrict__ bfb,  const float* __restrict__ Wsame,
    const float* __restrict__ Wdiff,
    const float* __restrict__ b1, const float* __restrict__ b2,
    const float* __restrict__ b3,
    const float* __restrict__ scalep,
    const u16* __restrict__ Wt,     // d_ws: 4 x [256][256] bf16 (transposed)
    float* __restrict__ out)
{
  // sR1: elec -> hmsg -> t1 -> t2 (padded [16][PDIM])
  // sB : beta f32 [16][24][16]
  // sE1: elec1 (padded)
  __shared__ float sR1[ROWS*PDIM];
  __shared__ float sB [ROWS*NNB*16];
  __shared__ float sE1[ROWS*PDIM];
  __shared__ int   sMask[ROWS*NNB];

  const int t  = threadIdx.x;
  const int n0 = blockIdx.x * ROWS;

  // ---- Phase 0: stage elec rows into sR1 (padded) ----
  {
    const float4* ep = (const float4*)elec;
    #pragma unroll
    for (int h = 0; h < 2; h++){
      const int idx = t + h*NT;                 // 0..1023 = 16 rows x 64 float4
      float4 v = ep[(size_t)n0*64 + idx];
      *(float4*)&sR1[(idx>>6)*PDIM + (idx&63)*4] = v;
    }
  }
  __syncthreads();

  // ---- GEMM1: elec1 = silu(elec @ W_in + b_in) -> sE1 ----
  gemm_mfma<0>(sR1, sE1, sR1, Wt, bin, nullptr, nullptr, 0.f, n0, t);

  // ---- Phase 2a: pairwise filter -> beta(sB) + spin mask (no barrier needed before) ----
  if (t < ROWS*NNB) {
    const int rr = t / NNB;
    const int k  = t - rr*NNB;
    const int n  = n0 + rr;
    const float* rp  = rpos + n*3;
    const float* rnp = rnb + (n*NNB + k)*3;
    float dx = rnp[0] - rp[0];
    float dy = rnp[1] - rp[1];
    float dz = rnp[2] - rp[2];
    float dist = sqrtf(dx*dx + dy*dy + dz*dz + 1e-12f);
    float feats[4] = {dist, dx, dy, dz};
    float h[32];
    #pragma unroll
    for (int f4 = 0; f4 < 8; f4++){
      float4 a4 = *(const float4*)&eeb[4*f4];     // lane-uniform -> s_load
      float av[4] = {a4.x, a4.y, a4.z, a4.w};
      #pragma unroll
      for (int i = 0; i < 4; i++){
        float4 kv = *(const float4*)&eek[i*32 + 4*f4];
        av[0]+=feats[i]*kv.x; av[1]+=feats[i]*kv.y; av[2]+=feats[i]*kv.z; av[3]+=feats[i]*kv.w;
      }
      h[4*f4+0]=fast_silu(av[0]); h[4*f4+1]=fast_silu(av[1]);
      h[4*f4+2]=fast_silu(av[2]); h[4*f4+3]=fast_silu(av[3]);
    }
    float env[8];
    #pragma unroll
    for (int e = 0; e < 8; e++){
      float q = dist * __builtin_amdgcn_rcpf(eesc[e]);
      env[e] = __builtin_amdgcn_exp2f(-1.44269504088896340f * q * q);
    }
    float xx = dist * (1.0f/CUTOFF);
    float cut = (dist < CUTOFF) ? (1.0f-xx)*(1.0f-xx)*(1.0f+2.0f*xx) : 0.0f;
    float* bout = &sB[(rr*NNB + k)*16];
    #pragma unroll
    for (int j4 = 0; j4 < 4; j4++){
      float4 a4 = *(const float4*)&bfb[4*j4];
      float av[4] = {a4.x, a4.y, a4.z, a4.w};
      #pragma unroll
      for (int f = 0; f < 40; f++){
        float val = (f < 32) ? h[f] : env[f-32];
        float4 wv = *(const float4*)&Wf[f*16 + 4*j4];
        av[0]+=val*wv.x; av[1]+=val*wv.y; av[2]+=val*wv.z; av[3]+=val*wv.w;
      }
      *(float4*)(bout + 4*j4) = make_float4(av[0]*cut, av[1]*cut, av[2]*cut, av[3]*cut);
    }
    sMask[rr*NNB + k] = (s[n] == snb[n*NNB + k]) ? 1 : 0;
  }
  __syncthreads();   // beta + sE1 ready; GEMM1 k-loop reads of sR1(elec) done

  // ---- Phase 2b: hmsg -> sR1 (overwrites dead elec). 128 thr/row-group, 2 dims ----
  {
    const int rg = t >> 7;           // 0..3
    const int d0 = (t & 127) << 1;
    float2 wsv[16], wdv[16];
    #pragma unroll
    for (int j = 0; j < 16; j++){
      wsv[j] = *(const float2*)(Wsame + j*DIM + d0);
      wdv[j] = *(const float2*)(Wdiff + j*DIM + d0);
    }
    for (int rr = 0; rr < 4; rr++){
      const int r = rg*4 + rr;
      const int n = n0 + r;
      float2 e1v = *(const float2*)&sE1[r*PDIM + d0];
      float ax = 0.f, ay = 0.f;
      for (int k = 0; k < NNB; k++){
        const float* bp = &sB[(r*NNB + k)*16];
        float bb[16];
        *(float4*)&bb[0]  = *(const float4*)(bp);
        *(float4*)&bb[4]  = *(const float4*)(bp+4);
        *(float4*)&bb[8]  = *(const float4*)(bp+8);
        *(float4*)&bb[12] = *(const float4*)(bp+12);
        float2 hv = *(const float2*)(hinit + ((size_t)(n*NNB + k) << 8) + d0);
        float sx = fast_silu(e1v.x + hv.x);
        float sy = fast_silu(e1v.y + hv.y);
        float gx = 0.f, gy = 0.f;
        if (sMask[r*NNB + k]){
          #pragma unroll
          for (int j = 0; j < 16; j++){ gx += bb[j]*wsv[j].x; gy += bb[j]*wsv[j].y; }
        } else {
          #pragma unroll
          for (int j = 0; j < 16; j++){ gx += bb[j]*wdv[j].x; gy += bb[j]*wdv[j].y; }
        }
        ax += sx*gx; ay += sy*gy;
      }
      *(float2*)&sR1[r*PDIM + d0] = make_float2(ax, ay);
    }
  }
  __syncthreads();

  const float scl = scalep[0];

  // ---- GEMM2: t1 = silu(elec1 @ W1 + b1 + hmsg) -> sR1 (in-place per owner) ----
  gemm_mfma<1>(sE1, sE1, sR1, Wt + (1<<16), b1, nullptr, nullptr, 0.f, n0, t);
  __syncthreads();
  // ---- GEMM3: t2 = silu(t1 @ W2 + b2 + msg) -> sR1 (inner barrier) ----
  gemm_mfma<2>(sR1, sE1, sR1, Wt + (2<<16), b2, msg, nullptr, 0.f, n0, t);
  __syncthreads();
  // ---- GEMM4: out = (silu(t2 @ W3 + b3) + elec1) * scl ----
  gemm_mfma<3>(sR1, sE1, sR1, Wt + (3<<16), b3, nullptr, out, scl, n0, t);
}

extern "C" void kernel_launch(void* const* d_in, const int* in_sizes, int n_in,
                              void* d_out, int out_size, void* d_ws, size_t ws_size,
                              hipStream_t stream) {
  (void)in_sizes; (void)n_in; (void)ws_size; (void)out_size;
  const float* elec  = (const float*)d_in[0];
  const float* msg   = (const float*)d_in[1];
  const float* rpos  = (const float*)d_in[2];
  const float* rnb   = (const float*)d_in[3];
  const int*   s     = (const int*)d_in[4];
  const int*   snb   = (const int*)d_in[5];
  const float* hinit = (const float*)d_in[6];
  const float* Win   = (const float*)d_in[7];
  const float* bin   = (const float*)d_in[8];
  const float* eesc  = (const float*)d_in[9];
  const float* eek   = (const float*)d_in[10];
  const float* eeb   = (const float*)d_in[11];
  const float* Wf    = (const float*)d_in[12];
  const float* bfb   = (const float*)d_in[13];
  const float* Wsame = (const float*)d_in[14];
  const float* Wdiff = (const float*)d_in[15];
  const float* W1    = (const float*)d_in[16];
  const float* b1    = (const float*)d_in[17];
  const float* W2    = (const float*)d_in[18];
  const float* b2    = (const float*)d_in[19];
  const float* W3    = (const float*)d_in[20];
  const float* b3    = (const float*)d_in[21];
  const float* scl   = (const float*)d_in[22];
  float* outp        = (float*)d_out;
  u16*   wt          = (u16*)d_ws;       // 512 KB used

  wprep<<<dim3(1024), dim3(256), 0, stream>>>(Win, W1, W2, W3, wt);
  fused_moon_kernel<<<dim3(NEL/ROWS), dim3(NT), 0, stream>>>(
      elec, msg, rpos, rnb, s, snb, hinit,
      bin, eesc, eek, eeb, Wf, bfb, Wsame, Wdiff,
      b1, b2, b3, scl, wt, outp);
}